// Round 6
// baseline (539.995 us; speedup 1.0000x reference)
//
#include <hip/hip_runtime.h>

// B=256, F=16, FO=32, J=22, H=8, IN=256, OUT=512, HID=64, HS=32
// Degenerate-einsum analysis:
//   attn_s = qsum (x) ksum  (outer product of channel sums)
//   x_s    = diag(softmax(attn_s)) * (sum_u v_s')
//   x_t    = sum_f v_t  (softmax sums to 1; q_t/k_t/conv_t/mask_t unused)
// Round 6: ONLY change vs round 5 — vproj3 __launch_bounds__(512,4)->(512,2).
// (512,4) capped VGPRs at 64 while the body needs ~110-140 (12 f32x4 accs
// alone = 48) -> accumulators spilled to scratch -> every MFMA round-tripped
// global memory. VGPR_Count=52 was the tell. (512,2) caps at 256: no spills.

#define NEGV (-1000000000.0f)

typedef __attribute__((ext_vector_type(8))) short short8;
typedef __attribute__((ext_vector_type(4))) float f32x4;

__device__ inline ushort f2bf(float f) {
  union { float f; unsigned u; } a;
  a.f = f;
  unsigned u = a.u;
  return (ushort)((u + 0x7FFFu + ((u >> 16) & 1u)) >> 16);  // RNE
}

// ---------------- prep: pre-summed weight columns (8 blocks) ----------------
__global__ __launch_bounds__(256) void prep_kernel(const float* __restrict__ Wq_w,
                                                   const float* __restrict__ Wq_b,
                                                   const float* __restrict__ Wk_w,
                                                   const float* __restrict__ Wk_b,
                                                   float* __restrict__ sqw, float* __restrict__ sqb,
                                                   float* __restrict__ skw, float* __restrict__ skb) {
  int idx = blockIdx.x * 256 + threadIdx.x;  // 0..2047
  int i = idx >> 3, m = idx & 7;
  const float4* qw = reinterpret_cast<const float4*>(Wq_w + i * 512 + m * 64);
  const float4* kw = reinterpret_cast<const float4*>(Wk_w + i * 512 + m * 64);
  float aq = 0.f, ak = 0.f;
  #pragma unroll
  for (int c4 = 0; c4 < 8; ++c4) {
    float4 x = qw[c4];
    float4 y = kw[c4];
    aq += x.x + x.y + x.z + x.w;
    ak += y.x + y.y + y.z + y.w;
  }
  sqw[i * 8 + m] = aq;
  skw[i * 8 + m] = ak;
  if (idx < 8) {
    float bq = 0.f, bk = 0.f;
    for (int c = 0; c < 32; ++c) { bq += Wq_b[idx * 64 + c]; bk += Wk_b[idx * 64 + c]; }
    sqb[idx] = bq;
    skb[idx] = bk;
  }
}

// ---------------- Wv -> bf16 swizzled to wave-fragment order ----------------
// wvtf[((nt*8 + ks)*64 + lane)*8 + e] = bf16(Wv[(ks*32 + (lane>>4)*8 + e)*512 + nt*16 + (lane&15)])
__global__ __launch_bounds__(512) void wvt_kernel(const float* __restrict__ Wv,
                                                  ushort* __restrict__ wvtf) {
  int idx = blockIdx.x * 512 + threadIdx.x;  // 0..131071
  int e = idx & 7;
  int lane = (idx >> 3) & 63;
  int ks = (idx >> 9) & 7;
  int nt = idx >> 12;
  int r0 = lane & 15, kb = lane >> 4;
  int k = ks * 32 + kb * 8 + e;
  int ch = nt * 16 + r0;
  wvtf[idx] = f2bf(Wv[k * 512 + ch]);
}

// ---------------- qsum[b][h][t][s] = sum_c q_s ----------------
__global__ __launch_bounds__(256) void qsum_kernel(const float* __restrict__ q,
                                                   const float* __restrict__ sqw,
                                                   const float* __restrict__ sqb,
                                                   float* __restrict__ qsum) {
  int blk = blockIdx.x;  // b*32 + fo2
  int fo2 = blk & 31;
  int b = blk >> 5;
  __shared__ float lq[22][257];
  __shared__ float lw[2048];
  __shared__ float lb[8];
  int tid = threadIdx.x;
  const float* qb = q + (size_t)blk * (22 * 256);
  #pragma unroll
  for (int j = 0; j < 22; ++j) lq[j][tid] = qb[j * 256 + tid];
  for (int r = tid; r < 2048; r += 256) lw[r] = sqw[r];
  if (tid < 8) lb[tid] = sqb[tid];
  __syncthreads();
  if (tid < 176) {
    int j2 = tid >> 3, m = tid & 7;
    float acc = lb[m];
    for (int i = 0; i < 256; ++i) acc += lq[j2][i] * lw[i * 8 + m];
    int lf = (fo2 & 3) * 11264 + j2 * 512 + m * 64;
    int t = lf / 1408;
    int s = (lf % 1408) >> 6;
    int h = fo2 >> 2;
    qsum[(((size_t)b * 8 + h) * 32 + t) * 22 + s] = acc;
  }
}

// ---------------- ksumraw[b][h][f][j] = sum_d k_s ----------------
__global__ __launch_bounds__(256) void ksum_kernel(const float* __restrict__ k,
                                                   const float* __restrict__ skw,
                                                   const float* __restrict__ skb,
                                                   float* __restrict__ ksumraw) {
  int blk = blockIdx.x;  // b*16 + f2
  int f2 = blk & 15;
  int b = blk >> 4;
  __shared__ float lk[22][257];
  __shared__ float lw[2048];
  __shared__ float lb[8];
  int tid = threadIdx.x;
  const float* kb = k + (size_t)blk * (22 * 256);
  #pragma unroll
  for (int j = 0; j < 22; ++j) lk[j][tid] = kb[j * 256 + tid];
  for (int r = tid; r < 2048; r += 256) lw[r] = skw[r];
  if (tid < 8) lb[tid] = skb[tid];
  __syncthreads();
  if (tid < 176) {
    int j2 = tid >> 3, m = tid & 7;
    float acc = lb[m];
    for (int i = 0; i < 256; ++i) acc += lk[j2][i] * lw[i * 8 + m];
    int lf = (f2 & 1) * 11264 + j2 * 512 + m * 64;
    int floc = lf / 1408;
    int j = (lf % 1408) >> 6;
    int h = f2 >> 1;
    ksumraw[(((size_t)b * 8 + h) * 16 + floc) * 22 + j] = acc;
  }
}

// ---------------- ksum_s = conv_s over ksumraw ----------------
__global__ void convk_kernel(const float* __restrict__ ksumraw, const float* __restrict__ csw,
                             const float* __restrict__ csb, float* __restrict__ ksum_s) {
  size_t idx = (size_t)blockIdx.x * 256 + threadIdx.x;
  if (idx >= (size_t)256 * 8 * 32 * 22) return;
  int j = (int)(idx % 22);
  size_t r = idx / 22;
  int o = (int)(r % 32);
  size_t bh = r / 32;
  float acc = 32.0f * csb[o];
  #pragma unroll
  for (int f = 0; f < 16; ++f) acc += csw[o * 16 + f] * ksumraw[(bh * 16 + f) * 22 + j];
  ksum_s[idx] = acc;
}

// ---------------- vproj3: one block per bh, single-shot ----------------
// A-LDS: 48 rows x 256 bf16, granule(8-ushort)-swizzled: gp = gl ^ (row&7).
// MFMA operands swapped: mfma(wvtf_frag /*M=channels*/, vrow_frag /*N=rows*/):
// lane holds D rows ch = nt*16 + kb*4 + reg (4 consecutive channels),
// col vrow = m*16 + r0. Scatter-reduce into vs_acc/vt_acc, write once.
__global__ __launch_bounds__(512, 2) void vproj3_kernel(const float* __restrict__ v,
                                                        const ushort* __restrict__ wvtf,
                                                        const float* __restrict__ Wv_b,
                                                        float* __restrict__ vs_inner,
                                                        float* __restrict__ vtsum) {
  int bh = blockIdx.x;  // 0..2047
  __shared__ ushort lA[48 * 256];
  __shared__ float vs_acc[512];
  __shared__ float vt_acc[704];
  int tid = threadIdx.x, lane = tid & 63, w = tid >> 6;
  int r0 = lane & 15, kb = lane >> 4;

  // stage 44x256 f32 -> bf16, swizzled granules (1408 groups of 8)
  const float* vsrc = v + (size_t)bh * 11264;
  {
    int g0 = tid, g1 = tid + 512, g2 = tid + 1024;
    float4 a0 = *reinterpret_cast<const float4*>(vsrc + g0 * 8);
    float4 b0 = *reinterpret_cast<const float4*>(vsrc + g0 * 8 + 4);
    float4 a1 = *reinterpret_cast<const float4*>(vsrc + g1 * 8);
    float4 b1 = *reinterpret_cast<const float4*>(vsrc + g1 * 8 + 4);
    float4 a2 = {0,0,0,0}, b2 = {0,0,0,0};
    if (g2 < 1408) {
      a2 = *reinterpret_cast<const float4*>(vsrc + g2 * 8);
      b2 = *reinterpret_cast<const float4*>(vsrc + g2 * 8 + 4);
    }
    #define PUT(g, pa, pb)                                                  \
      {                                                                     \
        int row_ = (g) >> 5, gl_ = (g) & 31;                                \
        int gp_ = gl_ ^ (row_ & 7);                                         \
        short8 u_;                                                          \
        u_[0] = (short)f2bf(pa.x); u_[1] = (short)f2bf(pa.y);               \
        u_[2] = (short)f2bf(pa.z); u_[3] = (short)f2bf(pa.w);               \
        u_[4] = (short)f2bf(pb.x); u_[5] = (short)f2bf(pb.y);               \
        u_[6] = (short)f2bf(pb.z); u_[7] = (short)f2bf(pb.w);               \
        *reinterpret_cast<short8*>(&lA[row_ * 256 + gp_ * 8]) = u_;         \
      }
    PUT(g0, a0, b0);
    PUT(g1, a1, b1);
    if (g2 < 1408) PUT(g2, a2, b2);
    if (tid < 128) {  // zero pad rows 44..47
      int g = 1408 + tid;
      int row_ = g >> 5, gp_ = (g & 31) ^ (row_ & 7);
      short8 z = {0, 0, 0, 0, 0, 0, 0, 0};
      *reinterpret_cast<short8*>(&lA[row_ * 256 + gp_ * 8]) = z;
    }
    #undef PUT
  }
  vs_acc[tid] = 0.f;
  if (tid < 704) vt_acc[tid] = 0.f;
  if (tid < 192) vt_acc[tid + 512] = 0.f;
  __syncthreads();

  // wave w owns n-tiles nt0..nt0+3 (channels w*64 .. w*64+63)
  int nt0 = w * 4;
  f32x4 acc[3][4];
  #pragma unroll
  for (int m = 0; m < 3; ++m)
    #pragma unroll
    for (int n = 0; n < 4; ++n) acc[m][n] = (f32x4){0.f, 0.f, 0.f, 0.f};

  #pragma unroll
  for (int ks = 0; ks < 8; ++ks) {
    int go = ((ks * 4 + kb) ^ (r0 & 7)) * 8;
    short8 a0 = *reinterpret_cast<const short8*>(&lA[(r0) * 256 + go]);
    short8 a1 = *reinterpret_cast<const short8*>(&lA[(16 + r0) * 256 + go]);
    short8 a2 = *reinterpret_cast<const short8*>(&lA[(32 + r0) * 256 + go]);
    #pragma unroll
    for (int n = 0; n < 4; ++n) {
      short8 bf = *reinterpret_cast<const short8*>(
          wvtf + ((size_t)((nt0 + n) * 8 + ks) * 64 + lane) * 8);
      // swapped: channels are the M operand, v-rows the N operand
      acc[0][n] = __builtin_amdgcn_mfma_f32_16x16x32_bf16(bf, a0, acc[0][n], 0, 0, 0);
      acc[1][n] = __builtin_amdgcn_mfma_f32_16x16x32_bf16(bf, a1, acc[1][n], 0, 0, 0);
      acc[2][n] = __builtin_amdgcn_mfma_f32_16x16x32_bf16(bf, a2, acc[2][n], 0, 0, 0);
    }
  }

  // scatter-reduce (no barrier needed before: accs are wave-private)
  #pragma unroll
  for (int n = 0; n < 4; ++n) {
    int ch_base = (nt0 + n) * 16 + kb * 4;  // 4 consecutive channels
    int c6 = ch_base >> 6, d0 = ch_base & 63;
    float4 bq = *reinterpret_cast<const float4*>(Wv_b + ch_base);
    #pragma unroll
    for (int m = 0; m < 3; ++m) {
      int vrow = m * 16 + r0;
      if (vrow >= 44) continue;
      int f2loc = (vrow >= 22) ? 1 : 0;
      int j = vrow - f2loc * 22;
      int fj = f2loc * 176 + j * 8 + c6;
      int f = fj / 22, jj = fj - f * 22;
      if (d0 < 32) {
        float* base = &vs_acc[f * 32 + d0];
        atomicAdd(base + 0, acc[m][n][0] + bq.x);
        atomicAdd(base + 1, acc[m][n][1] + bq.y);
        atomicAdd(base + 2, acc[m][n][2] + bq.z);
        atomicAdd(base + 3, acc[m][n][3] + bq.w);
      } else {
        float* base = &vt_acc[jj * 32 + (d0 - 32)];
        atomicAdd(base + 0, acc[m][n][0] + bq.x);
        atomicAdd(base + 1, acc[m][n][1] + bq.y);
        atomicAdd(base + 2, acc[m][n][2] + bq.z);
        atomicAdd(base + 3, acc[m][n][3] + bq.w);
      }
    }
  }
  __syncthreads();

  vs_inner[(size_t)bh * 512 + tid] = vs_acc[tid];
  if (tid < 704) vtsum[(size_t)bh * 704 + tid] = vt_acc[tid];
  if (tid < 192) vtsum[(size_t)bh * 704 + tid + 512] = vt_acc[tid + 512];
}

// ---------------- vssum = conv_s over vs_inner ----------------
__global__ void convv_kernel(const float* __restrict__ vs_inner, const float* __restrict__ csw,
                             const float* __restrict__ csb, float* __restrict__ vssum) {
  size_t idx = (size_t)blockIdx.x * 256 + threadIdx.x;
  if (idx >= (size_t)256 * 8 * 32 * 32) return;
  int d = (int)(idx & 31);
  size_t r = idx >> 5;
  int t = (int)(r & 31);
  size_t bh = r >> 5;
  float acc = 22.0f * csb[t];
  #pragma unroll
  for (int f = 0; f < 16; ++f) acc += csw[t * 16 + f] * vs_inner[(bh * 16 + f) * 32 + d];
  vssum[idx] = acc;
}

// ---------------- final: diag softmax + assemble output ----------------
__global__ __launch_bounds__(256) void final_kernel(const float* __restrict__ qsum,
                                                    const float* __restrict__ ksum_s,
                                                    const float* __restrict__ vssum,
                                                    const float* __restrict__ vtsum,
                                                    const int* __restrict__ mask_s,
                                                    float* __restrict__ out) {
  int blk = blockIdx.x;  // b*32 + t
  int t = blk & 31;
  int b = blk >> 5;
  __shared__ float ql[8][22], kl[8][22], vsl[8][32], dg[8][22];
  __shared__ float vtl[8][704];
  __shared__ int msk[484];
  int tid = threadIdx.x;
  size_t bbase = (size_t)b * 8;
  if (tid < 176) {
    int h = tid / 22, s = tid % 22;
    ql[h][s] = qsum[((bbase + h) * 32 + t) * 22 + s];
    kl[h][s] = ksum_s[((bbase + h) * 32 + t) * 22 + s];
  }
  {
    int h = tid >> 5, d = tid & 31;
    vsl[h][d] = vssum[((bbase + h) * 32 + t) * 32 + d];
  }
  for (int idx = tid; idx < 5632; idx += 256) {
    int h = idx / 704, r = idx % 704;
    vtl[h][r] = vtsum[(bbase + h) * 704 + r];
  }
  for (int idx = tid; idx < 484; idx += 256) msk[idx] = mask_s[idx];
  __syncthreads();
  if (tid < 176) {
    int h = tid / 22, s = tid % 22;
    float qv = ql[h][s];
    float mx = -3.0e38f;
    #pragma unroll
    for (int u = 0; u < 22; ++u) {
      float av = msk[s * 22 + u] ? qv * kl[h][u] : NEGV;
      mx = fmaxf(mx, av);
    }
    float den = 0.f;
    #pragma unroll
    for (int u = 0; u < 22; ++u) {
      float av = msk[s * 22 + u] ? qv * kl[h][u] : NEGV;
      den += expf(av - mx);
    }
    float as = msk[s * 22 + s] ? qv * kl[h][s] : NEGV;
    dg[h][s] = expf(as - mx) / den;
  }
  __syncthreads();
  float* ob = out + (size_t)blk * (22 * 512);
  for (int idx = tid; idx < 11264; idx += 256) {
    int s = idx >> 9;
    int ch = idx & 511;
    int h = ch >> 6;
    int d = ch & 63;
    float val = (d < 32) ? dg[h][s] * vsl[h][d] : vtl[h][s * 32 + (d & 31)];
    ob[idx] = val;
  }
}

extern "C" void kernel_launch(void* const* d_in, const int* in_sizes, int n_in,
                              void* d_out, int out_size, void* d_ws, size_t ws_size,
                              hipStream_t stream) {
  const float* q = (const float*)d_in[0];
  const float* k = (const float*)d_in[1];
  const float* v = (const float*)d_in[2];
  const int* mask_s = (const int*)d_in[3];
  const float* Wq_w = (const float*)d_in[5];
  const float* Wq_b = (const float*)d_in[6];
  const float* Wk_w = (const float*)d_in[7];
  const float* Wk_b = (const float*)d_in[8];
  const float* Wv_w = (const float*)d_in[9];
  const float* Wv_b = (const float*)d_in[10];
  const float* csw = (const float*)d_in[11];
  const float* csb = (const float*)d_in[12];
  float* out = (float*)d_out;

  float* ws = (float*)d_ws;
  float* sqw = ws;                          // 2048
  float* sqb = sqw + 2048;                  // 8
  float* skw = sqb + 8;                     // 2048
  float* skb = skw + 2048;                  // 8  -> 4112
  ushort* wvtf = (ushort*)(skb + 8);        // 131072 ushorts = 65536 floats
  float* qsum = (float*)(wvtf + 131072);    // 1441792
  float* ksumraw = qsum + 1441792;          // 720896
  float* ksum_s = ksumraw + 720896;         // 1441792
  float* vs_inner = ksum_s + 1441792;       // 2048*512 = 1048576
  float* vtsum = vs_inner + 1048576;        // 2048*704 = 1441792
  float* vssum = vtsum + 1441792;           // 2097152

  hipLaunchKernelGGL(prep_kernel, dim3(8), dim3(256), 0, stream,
                     Wq_w, Wq_b, Wk_w, Wk_b, sqw, sqb, skw, skb);
  hipLaunchKernelGGL(wvt_kernel, dim3(256), dim3(512), 0, stream, Wv_w, wvtf);
  hipLaunchKernelGGL(qsum_kernel, dim3(256 * 32), dim3(256), 0, stream, q, sqw, sqb, qsum);
  hipLaunchKernelGGL(ksum_kernel, dim3(256 * 16), dim3(256), 0, stream, k, skw, skb, ksumraw);
  hipLaunchKernelGGL(convk_kernel, dim3(5632), dim3(256), 0, stream, ksumraw, csw, csb, ksum_s);
  hipLaunchKernelGGL(vproj3_kernel, dim3(2048), dim3(512), 0, stream,
                     v, wvtf, Wv_b, vs_inner, vtsum);
  hipLaunchKernelGGL(convv_kernel, dim3(8192), dim3(256), 0, stream, vs_inner, csw, csb, vssum);
  hipLaunchKernelGGL(final_kernel, dim3(8192), dim3(256), 0, stream,
                     qsum, ksum_s, vssum, vtsum, mask_s, out);
}

// Round 7
// 431.759 us; speedup vs baseline: 1.2507x; 1.2507x over previous
//
#include <hip/hip_runtime.h>

// B=256, F=16, FO=32, J=22, H=8, IN=256, OUT=512, HID=64, HS=32
// Degenerate-einsum analysis:
//   attn_s = qsum (x) ksum  (outer product of channel sums)
//   x_s    = diag(softmax(attn_s)) * (sum_u v_s')
//   x_t    = sum_f v_t  (softmax sums to 1; q_t/k_t/conv_t/mask_t unused)
// Round 7: A/B within one round. Hypothesis: fp32 LDS atomicAdd lowers to a
// CAS loop (not ds_add_f32) -> ~45 contended CAS loops/thread = the invariant
// ~35us/bh across R2-R6. vproj3 (atomics) runs bh 0..1023; vproj4 (atomic-free
// dump/gather scatter) runs bh 1024..2047. rocprof gives both durs.

#define NEGV (-1000000000.0f)

typedef __attribute__((ext_vector_type(8))) short short8;
typedef __attribute__((ext_vector_type(4))) float f32x4;

__device__ inline ushort f2bf(float f) {
  union { float f; unsigned u; } a;
  a.f = f;
  unsigned u = a.u;
  return (ushort)((u + 0x7FFFu + ((u >> 16) & 1u)) >> 16);  // RNE
}

// ---------------- prep: pre-summed weight columns (8 blocks) ----------------
__global__ __launch_bounds__(256) void prep_kernel(const float* __restrict__ Wq_w,
                                                   const float* __restrict__ Wq_b,
                                                   const float* __restrict__ Wk_w,
                                                   const float* __restrict__ Wk_b,
                                                   float* __restrict__ sqw, float* __restrict__ sqb,
                                                   float* __restrict__ skw, float* __restrict__ skb) {
  int idx = blockIdx.x * 256 + threadIdx.x;  // 0..2047
  int i = idx >> 3, m = idx & 7;
  const float4* qw = reinterpret_cast<const float4*>(Wq_w + i * 512 + m * 64);
  const float4* kw = reinterpret_cast<const float4*>(Wk_w + i * 512 + m * 64);
  float aq = 0.f, ak = 0.f;
  #pragma unroll
  for (int c4 = 0; c4 < 8; ++c4) {
    float4 x = qw[c4];
    float4 y = kw[c4];
    aq += x.x + x.y + x.z + x.w;
    ak += y.x + y.y + y.z + y.w;
  }
  sqw[i * 8 + m] = aq;
  skw[i * 8 + m] = ak;
  if (idx < 8) {
    float bq = 0.f, bk = 0.f;
    for (int c = 0; c < 32; ++c) { bq += Wq_b[idx * 64 + c]; bk += Wk_b[idx * 64 + c]; }
    sqb[idx] = bq;
    skb[idx] = bk;
  }
}

// ---------------- Wv -> bf16 swizzled to wave-fragment order ----------------
__global__ __launch_bounds__(512) void wvt_kernel(const float* __restrict__ Wv,
                                                  ushort* __restrict__ wvtf) {
  int idx = blockIdx.x * 512 + threadIdx.x;  // 0..131071
  int e = idx & 7;
  int lane = (idx >> 3) & 63;
  int ks = (idx >> 9) & 7;
  int nt = idx >> 12;
  int r0 = lane & 15, kb = lane >> 4;
  int k = ks * 32 + kb * 8 + e;
  int ch = nt * 16 + r0;
  wvtf[idx] = f2bf(Wv[k * 512 + ch]);
}

// ---------------- qsum[b][h][t][s] = sum_c q_s ----------------
__global__ __launch_bounds__(256) void qsum_kernel(const float* __restrict__ q,
                                                   const float* __restrict__ sqw,
                                                   const float* __restrict__ sqb,
                                                   float* __restrict__ qsum) {
  int blk = blockIdx.x;  // b*32 + fo2
  int fo2 = blk & 31;
  int b = blk >> 5;
  __shared__ float lq[22][257];
  __shared__ float lw[2048];
  __shared__ float lb[8];
  int tid = threadIdx.x;
  const float* qb = q + (size_t)blk * (22 * 256);
  #pragma unroll
  for (int j = 0; j < 22; ++j) lq[j][tid] = qb[j * 256 + tid];
  for (int r = tid; r < 2048; r += 256) lw[r] = sqw[r];
  if (tid < 8) lb[tid] = sqb[tid];
  __syncthreads();
  if (tid < 176) {
    int j2 = tid >> 3, m = tid & 7;
    float acc = lb[m];
    for (int i = 0; i < 256; ++i) acc += lq[j2][i] * lw[i * 8 + m];
    int lf = (fo2 & 3) * 11264 + j2 * 512 + m * 64;
    int t = lf / 1408;
    int s = (lf % 1408) >> 6;
    int h = fo2 >> 2;
    qsum[(((size_t)b * 8 + h) * 32 + t) * 22 + s] = acc;
  }
}

// ---------------- ksumraw[b][h][f][j] = sum_d k_s ----------------
__global__ __launch_bounds__(256) void ksum_kernel(const float* __restrict__ k,
                                                   const float* __restrict__ skw,
                                                   const float* __restrict__ skb,
                                                   float* __restrict__ ksumraw) {
  int blk = blockIdx.x;  // b*16 + f2
  int f2 = blk & 15;
  int b = blk >> 4;
  __shared__ float lk[22][257];
  __shared__ float lw[2048];
  __shared__ float lb[8];
  int tid = threadIdx.x;
  const float* kb = k + (size_t)blk * (22 * 256);
  #pragma unroll
  for (int j = 0; j < 22; ++j) lk[j][tid] = kb[j * 256 + tid];
  for (int r = tid; r < 2048; r += 256) lw[r] = skw[r];
  if (tid < 8) lb[tid] = skb[tid];
  __syncthreads();
  if (tid < 176) {
    int j2 = tid >> 3, m = tid & 7;
    float acc = lb[m];
    for (int i = 0; i < 256; ++i) acc += lk[j2][i] * lw[i * 8 + m];
    int lf = (f2 & 1) * 11264 + j2 * 512 + m * 64;
    int floc = lf / 1408;
    int j = (lf % 1408) >> 6;
    int h = f2 >> 1;
    ksumraw[(((size_t)b * 8 + h) * 16 + floc) * 22 + j] = acc;
  }
}

// ---------------- ksum_s = conv_s over ksumraw ----------------
__global__ void convk_kernel(const float* __restrict__ ksumraw, const float* __restrict__ csw,
                             const float* __restrict__ csb, float* __restrict__ ksum_s) {
  size_t idx = (size_t)blockIdx.x * 256 + threadIdx.x;
  if (idx >= (size_t)256 * 8 * 32 * 22) return;
  int j = (int)(idx % 22);
  size_t r = idx / 22;
  int o = (int)(r % 32);
  size_t bh = r / 32;
  float acc = 32.0f * csb[o];
  #pragma unroll
  for (int f = 0; f < 16; ++f) acc += csw[o * 16 + f] * ksumraw[(bh * 16 + f) * 22 + j];
  ksum_s[idx] = acc;
}

// ================ vproj3: CONTROL (LDS atomics), bh0..bh0+grid ================
__global__ __launch_bounds__(512, 2) void vproj3_kernel(const float* __restrict__ v,
                                                        const ushort* __restrict__ wvtf,
                                                        const float* __restrict__ Wv_b,
                                                        float* __restrict__ vs_inner,
                                                        float* __restrict__ vtsum,
                                                        int bh0) {
  int bh = blockIdx.x + bh0;
  __shared__ ushort lA[48 * 256];
  __shared__ float vs_acc[512];
  __shared__ float vt_acc[704];
  int tid = threadIdx.x, lane = tid & 63, w = tid >> 6;
  int r0 = lane & 15, kb = lane >> 4;

  const float* vsrc = v + (size_t)bh * 11264;
  {
    int g0 = tid, g1 = tid + 512, g2 = tid + 1024;
    float4 a0 = *reinterpret_cast<const float4*>(vsrc + g0 * 8);
    float4 b0 = *reinterpret_cast<const float4*>(vsrc + g0 * 8 + 4);
    float4 a1 = *reinterpret_cast<const float4*>(vsrc + g1 * 8);
    float4 b1 = *reinterpret_cast<const float4*>(vsrc + g1 * 8 + 4);
    float4 a2 = {0,0,0,0}, b2 = {0,0,0,0};
    if (g2 < 1408) {
      a2 = *reinterpret_cast<const float4*>(vsrc + g2 * 8);
      b2 = *reinterpret_cast<const float4*>(vsrc + g2 * 8 + 4);
    }
    #define PUT(g, pa, pb)                                                  \
      {                                                                     \
        int row_ = (g) >> 5, gl_ = (g) & 31;                                \
        int gp_ = gl_ ^ (row_ & 7);                                         \
        short8 u_;                                                          \
        u_[0] = (short)f2bf(pa.x); u_[1] = (short)f2bf(pa.y);               \
        u_[2] = (short)f2bf(pa.z); u_[3] = (short)f2bf(pa.w);               \
        u_[4] = (short)f2bf(pb.x); u_[5] = (short)f2bf(pb.y);               \
        u_[6] = (short)f2bf(pb.z); u_[7] = (short)f2bf(pb.w);               \
        *reinterpret_cast<short8*>(&lA[row_ * 256 + gp_ * 8]) = u_;         \
      }
    PUT(g0, a0, b0);
    PUT(g1, a1, b1);
    if (g2 < 1408) PUT(g2, a2, b2);
    if (tid < 128) {
      int g = 1408 + tid;
      int row_ = g >> 5, gp_ = (g & 31) ^ (row_ & 7);
      short8 z = {0, 0, 0, 0, 0, 0, 0, 0};
      *reinterpret_cast<short8*>(&lA[row_ * 256 + gp_ * 8]) = z;
    }
    #undef PUT
  }
  vs_acc[tid] = 0.f;
  if (tid < 704) vt_acc[tid] = 0.f;
  if (tid < 192) vt_acc[tid + 512] = 0.f;
  __syncthreads();

  int nt0 = w * 4;
  f32x4 acc[3][4];
  #pragma unroll
  for (int m = 0; m < 3; ++m)
    #pragma unroll
    for (int n = 0; n < 4; ++n) acc[m][n] = (f32x4){0.f, 0.f, 0.f, 0.f};

  #pragma unroll
  for (int ks = 0; ks < 8; ++ks) {
    int go = ((ks * 4 + kb) ^ (r0 & 7)) * 8;
    short8 a0 = *reinterpret_cast<const short8*>(&lA[(r0) * 256 + go]);
    short8 a1 = *reinterpret_cast<const short8*>(&lA[(16 + r0) * 256 + go]);
    short8 a2 = *reinterpret_cast<const short8*>(&lA[(32 + r0) * 256 + go]);
    #pragma unroll
    for (int n = 0; n < 4; ++n) {
      short8 bf = *reinterpret_cast<const short8*>(
          wvtf + ((size_t)((nt0 + n) * 8 + ks) * 64 + lane) * 8);
      acc[0][n] = __builtin_amdgcn_mfma_f32_16x16x32_bf16(bf, a0, acc[0][n], 0, 0, 0);
      acc[1][n] = __builtin_amdgcn_mfma_f32_16x16x32_bf16(bf, a1, acc[1][n], 0, 0, 0);
      acc[2][n] = __builtin_amdgcn_mfma_f32_16x16x32_bf16(bf, a2, acc[2][n], 0, 0, 0);
    }
  }

  #pragma unroll
  for (int n = 0; n < 4; ++n) {
    int ch_base = (nt0 + n) * 16 + kb * 4;
    int c6 = ch_base >> 6, d0 = ch_base & 63;
    float4 bq = *reinterpret_cast<const float4*>(Wv_b + ch_base);
    #pragma unroll
    for (int m = 0; m < 3; ++m) {
      int vrow = m * 16 + r0;
      if (vrow >= 44) continue;
      int f2loc = (vrow >= 22) ? 1 : 0;
      int j = vrow - f2loc * 22;
      int fj = f2loc * 176 + j * 8 + c6;
      int f = fj / 22, jj = fj - f * 22;
      if (d0 < 32) {
        float* base = &vs_acc[f * 32 + d0];
        atomicAdd(base + 0, acc[m][n][0] + bq.x);
        atomicAdd(base + 1, acc[m][n][1] + bq.y);
        atomicAdd(base + 2, acc[m][n][2] + bq.z);
        atomicAdd(base + 3, acc[m][n][3] + bq.w);
      } else {
        float* base = &vt_acc[jj * 32 + (d0 - 32)];
        atomicAdd(base + 0, acc[m][n][0] + bq.x);
        atomicAdd(base + 1, acc[m][n][1] + bq.y);
        atomicAdd(base + 2, acc[m][n][2] + bq.z);
        atomicAdd(base + 3, acc[m][n][3] + bq.w);
      }
    }
  }
  __syncthreads();

  vs_inner[(size_t)bh * 512 + tid] = vs_acc[tid];
  if (tid < 704) vtsum[(size_t)bh * 704 + tid] = vt_acc[tid];
  if (tid < 192) vtsum[(size_t)bh * 704 + tid + 512] = vt_acc[tid + 512];
}

// ================ vproj4: NO ATOMICS — dump/gather scatter ================
// Same stage+MFMA. Then: each lane plain-writes its 24 values (n-phase) to a
// private LDS slot (stride 25 words, bank-spread); each output gathers its
// 22 (vs) / 16 (vt) contributors via closed-form index inversion. Zero atomics.
__global__ __launch_bounds__(512, 2) void vproj4_kernel(const float* __restrict__ v,
                                                        const ushort* __restrict__ wvtf,
                                                        const float* __restrict__ Wv_b,
                                                        float* __restrict__ vs_inner,
                                                        float* __restrict__ vtsum,
                                                        int bh0) {
  int bh = blockIdx.x + bh0;
  __shared__ ushort smem_u[25600];  // 51.2 KB; [0,24576)B = lA during MFMA, whole = dump after
  ushort* lA = smem_u;
  float* dump = reinterpret_cast<float*>(smem_u);
  int tid = threadIdx.x, lane = tid & 63, w = tid >> 6;
  int r0 = lane & 15, kb = lane >> 4;

  const float* vsrc = v + (size_t)bh * 11264;
  {
    int g0 = tid, g1 = tid + 512, g2 = tid + 1024;
    float4 a0 = *reinterpret_cast<const float4*>(vsrc + g0 * 8);
    float4 b0 = *reinterpret_cast<const float4*>(vsrc + g0 * 8 + 4);
    float4 a1 = *reinterpret_cast<const float4*>(vsrc + g1 * 8);
    float4 b1 = *reinterpret_cast<const float4*>(vsrc + g1 * 8 + 4);
    float4 a2 = {0,0,0,0}, b2 = {0,0,0,0};
    if (g2 < 1408) {
      a2 = *reinterpret_cast<const float4*>(vsrc + g2 * 8);
      b2 = *reinterpret_cast<const float4*>(vsrc + g2 * 8 + 4);
    }
    #define PUT(g, pa, pb)                                                  \
      {                                                                     \
        int row_ = (g) >> 5, gl_ = (g) & 31;                                \
        int gp_ = gl_ ^ (row_ & 7);                                         \
        short8 u_;                                                          \
        u_[0] = (short)f2bf(pa.x); u_[1] = (short)f2bf(pa.y);               \
        u_[2] = (short)f2bf(pa.z); u_[3] = (short)f2bf(pa.w);               \
        u_[4] = (short)f2bf(pb.x); u_[5] = (short)f2bf(pb.y);               \
        u_[6] = (short)f2bf(pb.z); u_[7] = (short)f2bf(pb.w);               \
        *reinterpret_cast<short8*>(&lA[row_ * 256 + gp_ * 8]) = u_;         \
      }
    PUT(g0, a0, b0);
    PUT(g1, a1, b1);
    if (g2 < 1408) PUT(g2, a2, b2);
    if (tid < 128) {
      int g = 1408 + tid;
      int row_ = g >> 5, gp_ = (g & 31) ^ (row_ & 7);
      short8 z = {0, 0, 0, 0, 0, 0, 0, 0};
      *reinterpret_cast<short8*>(&lA[row_ * 256 + gp_ * 8]) = z;
    }
    #undef PUT
  }
  __syncthreads();

  int nt0 = w * 4;
  f32x4 acc[3][4];
  #pragma unroll
  for (int m = 0; m < 3; ++m)
    #pragma unroll
    for (int n = 0; n < 4; ++n) acc[m][n] = (f32x4){0.f, 0.f, 0.f, 0.f};

  #pragma unroll
  for (int ks = 0; ks < 8; ++ks) {
    int go = ((ks * 4 + kb) ^ (r0 & 7)) * 8;
    short8 a0 = *reinterpret_cast<const short8*>(&lA[(r0) * 256 + go]);
    short8 a1 = *reinterpret_cast<const short8*>(&lA[(16 + r0) * 256 + go]);
    short8 a2 = *reinterpret_cast<const short8*>(&lA[(32 + r0) * 256 + go]);
    #pragma unroll
    for (int n = 0; n < 4; ++n) {
      short8 bf = *reinterpret_cast<const short8*>(
          wvtf + ((size_t)((nt0 + n) * 8 + ks) * 64 + lane) * 8);
      acc[0][n] = __builtin_amdgcn_mfma_f32_16x16x32_bf16(bf, a0, acc[0][n], 0, 0, 0);
      acc[1][n] = __builtin_amdgcn_mfma_f32_16x16x32_bf16(bf, a1, acc[1][n], 0, 0, 0);
      acc[2][n] = __builtin_amdgcn_mfma_f32_16x16x32_bf16(bf, a2, acc[2][n], 0, 0, 0);
    }
  }
  __syncthreads();  // all lA reads done before dump overwrites

  int dbase = (w * 64 + lane) * 25;
  // ---- phase A dump: n = 0,1 (vs channels d = n*16+kb*4+reg < 32) ----
  #pragma unroll
  for (int n = 0; n < 2; ++n) {
    float4 bq = *reinterpret_cast<const float4*>(Wv_b + w * 64 + n * 16 + kb * 4);
    #pragma unroll
    for (int m = 0; m < 3; ++m) {
      dump[dbase + n * 12 + m * 4 + 0] = acc[m][n][0] + bq.x;
      dump[dbase + n * 12 + m * 4 + 1] = acc[m][n][1] + bq.y;
      dump[dbase + n * 12 + m * 4 + 2] = acc[m][n][2] + bq.z;
      dump[dbase + n * 12 + m * 4 + 3] = acc[m][n][3] + bq.w;
    }
  }
  __syncthreads();
  // ---- vs gather: 512 outputs, 22 contributors each ----
  {
    int f = tid >> 5, d = tid & 31;
    int n = d >> 4, kb2 = (d >> 2) & 3, reg = d & 3;
    float s = 0.f;
    #pragma unroll
    for (int u = 0; u < 22; ++u) {
      int fj = f * 22 + u;
      int f2 = (fj >= 176) ? 1 : 0;
      int rem = fj - f2 * 176;
      int j = rem >> 3, ww = rem & 7;
      int vrow = f2 * 22 + j;
      int m = vrow >> 4, rr = vrow & 15;
      s += dump[(ww * 64 + kb2 * 16 + rr) * 25 + n * 12 + m * 4 + reg];
    }
    vs_inner[(size_t)bh * 512 + tid] = s;
  }
  __syncthreads();
  // ---- phase B dump: n = 2,3 (vt channels g = d-32) ----
  #pragma unroll
  for (int n = 2; n < 4; ++n) {
    float4 bq = *reinterpret_cast<const float4*>(Wv_b + w * 64 + n * 16 + kb * 4);
    #pragma unroll
    for (int m = 0; m < 3; ++m) {
      dump[dbase + (n - 2) * 12 + m * 4 + 0] = acc[m][n][0] + bq.x;
      dump[dbase + (n - 2) * 12 + m * 4 + 1] = acc[m][n][1] + bq.y;
      dump[dbase + (n - 2) * 12 + m * 4 + 2] = acc[m][n][2] + bq.z;
      dump[dbase + (n - 2) * 12 + m * 4 + 3] = acc[m][n][3] + bq.w;
    }
  }
  __syncthreads();
  // ---- vt gather: 704 outputs, 16 contributors each ----
  for (int o = tid; o < 704; o += 512) {
    int jj = o >> 5, g = o & 31;
    int nn = g >> 4, kb2 = (g >> 2) & 3, reg = g & 3;
    float s = 0.f;
    #pragma unroll
    for (int f = 0; f < 16; ++f) {
      int fj = f * 22 + jj;
      int f2 = (fj >= 176) ? 1 : 0;
      int rem = fj - f2 * 176;
      int j = rem >> 3, ww = rem & 7;
      int vrow = f2 * 22 + j;
      int m = vrow >> 4, rr = vrow & 15;
      s += dump[(ww * 64 + kb2 * 16 + rr) * 25 + nn * 12 + m * 4 + reg];
    }
    vtsum[(size_t)bh * 704 + o] = s;
  }
}

// ---------------- vssum = conv_s over vs_inner ----------------
__global__ void convv_kernel(const float* __restrict__ vs_inner, const float* __restrict__ csw,
                             const float* __restrict__ csb, float* __restrict__ vssum) {
  size_t idx = (size_t)blockIdx.x * 256 + threadIdx.x;
  if (idx >= (size_t)256 * 8 * 32 * 32) return;
  int d = (int)(idx & 31);
  size_t r = idx >> 5;
  int t = (int)(r & 31);
  size_t bh = r >> 5;
  float acc = 22.0f * csb[t];
  #pragma unroll
  for (int f = 0; f < 16; ++f) acc += csw[t * 16 + f] * vs_inner[(bh * 16 + f) * 32 + d];
  vssum[idx] = acc;
}

// ---------------- final: diag softmax + assemble output ----------------
__global__ __launch_bounds__(256) void final_kernel(const float* __restrict__ qsum,
                                                    const float* __restrict__ ksum_s,
                                                    const float* __restrict__ vssum,
                                                    const float* __restrict__ vtsum,
                                                    const int* __restrict__ mask_s,
                                                    float* __restrict__ out) {
  int blk = blockIdx.x;  // b*32 + t
  int t = blk & 31;
  int b = blk >> 5;
  __shared__ float ql[8][22], kl[8][22], vsl[8][32], dg[8][22];
  __shared__ float vtl[8][704];
  __shared__ int msk[484];
  int tid = threadIdx.x;
  size_t bbase = (size_t)b * 8;
  if (tid < 176) {
    int h = tid / 22, s = tid % 22;
    ql[h][s] = qsum[((bbase + h) * 32 + t) * 22 + s];
    kl[h][s] = ksum_s[((bbase + h) * 32 + t) * 22 + s];
  }
  {
    int h = tid >> 5, d = tid & 31;
    vsl[h][d] = vssum[((bbase + h) * 32 + t) * 32 + d];
  }
  for (int idx = tid; idx < 5632; idx += 256) {
    int h = idx / 704, r = idx % 704;
    vtl[h][r] = vtsum[(bbase + h) * 704 + r];
  }
  for (int idx = tid; idx < 484; idx += 256) msk[idx] = mask_s[idx];
  __syncthreads();
  if (tid < 176) {
    int h = tid / 22, s = tid % 22;
    float qv = ql[h][s];
    float mx = -3.0e38f;
    #pragma unroll
    for (int u = 0; u < 22; ++u) {
      float av = msk[s * 22 + u] ? qv * kl[h][u] : NEGV;
      mx = fmaxf(mx, av);
    }
    float den = 0.f;
    #pragma unroll
    for (int u = 0; u < 22; ++u) {
      float av = msk[s * 22 + u] ? qv * kl[h][u] : NEGV;
      den += expf(av - mx);
    }
    float as = msk[s * 22 + s] ? qv * kl[h][s] : NEGV;
    dg[h][s] = expf(as - mx) / den;
  }
  __syncthreads();
  float* ob = out + (size_t)blk * (22 * 512);
  for (int idx = tid; idx < 11264; idx += 256) {
    int s = idx >> 9;
    int ch = idx & 511;
    int h = ch >> 6;
    int d = ch & 63;
    float val = (d < 32) ? dg[h][s] * vsl[h][d] : vtl[h][s * 32 + (d & 31)];
    ob[idx] = val;
  }
}

extern "C" void kernel_launch(void* const* d_in, const int* in_sizes, int n_in,
                              void* d_out, int out_size, void* d_ws, size_t ws_size,
                              hipStream_t stream) {
  const float* q = (const float*)d_in[0];
  const float* k = (const float*)d_in[1];
  const float* v = (const float*)d_in[2];
  const int* mask_s = (const int*)d_in[3];
  const float* Wq_w = (const float*)d_in[5];
  const float* Wq_b = (const float*)d_in[6];
  const float* Wk_w = (const float*)d_in[7];
  const float* Wk_b = (const float*)d_in[8];
  const float* Wv_w = (const float*)d_in[9];
  const float* Wv_b = (const float*)d_in[10];
  const float* csw = (const float*)d_in[11];
  const float* csb = (const float*)d_in[12];
  float* out = (float*)d_out;

  float* ws = (float*)d_ws;
  float* sqw = ws;                          // 2048
  float* sqb = sqw + 2048;                  // 8
  float* skw = sqb + 8;                     // 2048
  float* skb = skw + 2048;                  // 8  -> 4112
  ushort* wvtf = (ushort*)(skb + 8);        // 131072 ushorts = 65536 floats
  float* qsum = (float*)(wvtf + 131072);    // 1441792
  float* ksumraw = qsum + 1441792;          // 720896
  float* ksum_s = ksumraw + 720896;         // 1441792
  float* vs_inner = ksum_s + 1441792;       // 2048*512 = 1048576
  float* vtsum = vs_inner + 1048576;        // 2048*704 = 1441792
  float* vssum = vtsum + 1441792;           // 2097152

  hipLaunchKernelGGL(prep_kernel, dim3(8), dim3(256), 0, stream,
                     Wq_w, Wq_b, Wk_w, Wk_b, sqw, sqb, skw, skb);
  hipLaunchKernelGGL(wvt_kernel, dim3(256), dim3(512), 0, stream, Wv_w, wvtf);
  hipLaunchKernelGGL(qsum_kernel, dim3(256 * 32), dim3(256), 0, stream, q, sqw, sqb, qsum);
  hipLaunchKernelGGL(ksum_kernel, dim3(256 * 16), dim3(256), 0, stream, k, skw, skb, ksumraw);
  hipLaunchKernelGGL(convk_kernel, dim3(5632), dim3(256), 0, stream, ksumraw, csw, csb, ksum_s);
  // A/B: control (atomics) on bh 0..1023, dump/gather on bh 1024..2047
  hipLaunchKernelGGL(vproj3_kernel, dim3(1024), dim3(512), 0, stream,
                     v, wvtf, Wv_b, vs_inner, vtsum, 0);
  hipLaunchKernelGGL(vproj4_kernel, dim3(1024), dim3(512), 0, stream,
                     v, wvtf, Wv_b, vs_inner, vtsum, 1024);
  hipLaunchKernelGGL(convv_kernel, dim3(8192), dim3(256), 0, stream, vs_inner, csw, csb, vssum);
  hipLaunchKernelGGL(final_kernel, dim3(8192), dim3(256), 0, stream,
                     qsum, ksum_s, vssum, vtsum, mask_s, out);
}

// Round 8
// 281.156 us; speedup vs baseline: 1.9206x; 1.5357x over previous
//
#include <hip/hip_runtime.h>

// B=256, F=16, FO=32, J=22, H=8, IN=256, OUT=512, HID=64, HS=32
// Degenerate-einsum analysis:
//   attn_s = qsum (x) ksum  (outer product of channel sums)
//   x_s    = diag(softmax(attn_s)) * (sum_u v_s')
//   x_t    = sum_f v_t  (softmax sums to 1; q_t/k_t/conv_t/mask_t unused)
// Round 8: R7 A/B confirmed LDS fp32 atomicAdd = CAS-loop disaster (3.7x).
//  - vproj4 (dump/gather) everywhere; LDS shrunk to 26.6KB via 4 phases.
//  - qsum/ksum -> MFMA template (stage 44 rows + 24 MFMA + plain scatter
//    stores vs summed-weight fragments). No atomics anywhere.
//  - final_kernel float4 stores + float4 vtl staging.

#define NEGV (-1000000000.0f)

typedef __attribute__((ext_vector_type(8))) short short8;
typedef __attribute__((ext_vector_type(4))) float f32x4;

__device__ inline ushort f2bf(float f) {
  union { float f; unsigned u; } a;
  a.f = f;
  unsigned u = a.u;
  return (ushort)((u + 0x7FFFu + ((u >> 16) & 1u)) >> 16);  // RNE
}

// stage 44 rows x 256 f32 -> bf16 into lA with granule swizzle gp = gl ^ (row&7)
#define STAGE44(SRCPTR)                                                        \
  {                                                                            \
    const float* vsrc_ = (SRCPTR);                                             \
    int g0 = tid, g1 = tid + 512, g2 = tid + 1024;                             \
    float4 a0 = *reinterpret_cast<const float4*>(vsrc_ + g0 * 8);              \
    float4 b0 = *reinterpret_cast<const float4*>(vsrc_ + g0 * 8 + 4);          \
    float4 a1 = *reinterpret_cast<const float4*>(vsrc_ + g1 * 8);              \
    float4 b1 = *reinterpret_cast<const float4*>(vsrc_ + g1 * 8 + 4);          \
    float4 a2 = {0, 0, 0, 0}, b2 = {0, 0, 0, 0};                               \
    if (g2 < 1408) {                                                           \
      a2 = *reinterpret_cast<const float4*>(vsrc_ + g2 * 8);                   \
      b2 = *reinterpret_cast<const float4*>(vsrc_ + g2 * 8 + 4);               \
    }                                                                          \
    PUTG(g0, a0, b0);                                                          \
    PUTG(g1, a1, b1);                                                          \
    if (g2 < 1408) PUTG(g2, a2, b2);                                           \
    if (tid < 128) {                                                           \
      int g = 1408 + tid;                                                      \
      int row_ = g >> 5, gp_ = (g & 31) ^ (row_ & 7);                          \
      short8 z = {0, 0, 0, 0, 0, 0, 0, 0};                                     \
      *reinterpret_cast<short8*>(&lA[row_ * 256 + gp_ * 8]) = z;               \
    }                                                                          \
  }

#define PUTG(g, pa, pb)                                                        \
  {                                                                            \
    int row_ = (g) >> 5, gl_ = (g) & 31;                                       \
    int gp_ = gl_ ^ (row_ & 7);                                                \
    short8 u_;                                                                 \
    u_[0] = (short)f2bf(pa.x); u_[1] = (short)f2bf(pa.y);                      \
    u_[2] = (short)f2bf(pa.z); u_[3] = (short)f2bf(pa.w);                      \
    u_[4] = (short)f2bf(pb.x); u_[5] = (short)f2bf(pb.y);                      \
    u_[6] = (short)f2bf(pb.z); u_[7] = (short)f2bf(pb.w);                      \
    *reinterpret_cast<short8*>(&lA[row_ * 256 + gp_ * 8]) = u_;                \
  }

// ---------------- prepb: summed biases ----------------
__global__ void prepb_kernel(const float* __restrict__ Wq_b, const float* __restrict__ Wk_b,
                             float* __restrict__ sqb, float* __restrict__ skb) {
  int m = threadIdx.x;
  if (m < 8) {
    float s = 0.f;
    for (int c = 0; c < 32; ++c) s += Wq_b[m * 64 + c];
    sqb[m] = s;
  } else if (m < 16) {
    int mm = m - 8;
    float s = 0.f;
    for (int c = 0; c < 32; ++c) s += Wk_b[mm * 64 + c];
    skb[mm] = s;
  }
}

// ---------------- qkwf: summed-weight MFMA B-fragments (bf16) ----------------
// frag[(ks*64+lane)*8+e] = bf16( sum_{c<32} W[(ks*32+(lane>>4)*8+e)*512 + (lane&15)*64 + c] )
// for (lane&15)<8, else 0.
__global__ __launch_bounds__(512) void qkwf_kernel(const float* __restrict__ Wq_w,
                                                   const float* __restrict__ Wk_w,
                                                   ushort* __restrict__ qwf,
                                                   ushort* __restrict__ kwf) {
  int idx = blockIdx.x * 512 + threadIdx.x;  // 0..8191
  int which = idx >> 12;
  int r = idx & 4095;
  int e = r & 7;
  int lane = (r >> 3) & 63;
  int ks = r >> 9;
  int m = lane & 15, kb = lane >> 4;
  int k = ks * 32 + kb * 8 + e;
  float s = 0.f;
  if (m < 8) {
    const float* W = which ? Wk_w : Wq_w;
    const float4* p = reinterpret_cast<const float4*>(W + (size_t)k * 512 + m * 64);
    #pragma unroll
    for (int c4 = 0; c4 < 8; ++c4) {
      float4 x = p[c4];
      s += x.x + x.y + x.z + x.w;
    }
  }
  (which ? kwf : qwf)[r] = f2bf(s);
}

// ---------------- Wv -> bf16 swizzled to wave-fragment order ----------------
__global__ __launch_bounds__(512) void wvt_kernel(const float* __restrict__ Wv,
                                                  ushort* __restrict__ wvtf) {
  int idx = blockIdx.x * 512 + threadIdx.x;  // 0..131071
  int e = idx & 7;
  int lane = (idx >> 3) & 63;
  int ks = (idx >> 9) & 7;
  int nt = idx >> 12;
  int r0 = lane & 15, kb = lane >> 4;
  int k = ks * 32 + kb * 8 + e;
  int ch = nt * 16 + r0;
  wvtf[idx] = f2bf(Wv[k * 512 + ch]);
}

// ---------------- qsum2: MFMA channel-sums for q ----------------
// block = (b, fo2-pair): stage 44 rows, 3 waves x 8 MFMA, plain scatter stores.
__global__ __launch_bounds__(512, 2) void qsum2_kernel(const float* __restrict__ q,
                                                       const ushort* __restrict__ qwf,
                                                       const float* __restrict__ sqb,
                                                       float* __restrict__ qsum) {
  int blk = blockIdx.x;  // b*16 + fp
  int fp = blk & 15, b = blk >> 4;
  __shared__ ushort lA[48 * 256];
  int tid = threadIdx.x, lane = tid & 63, w = tid >> 6;
  int r0 = lane & 15, kb = lane >> 4;
  STAGE44(q + (size_t)blk * 11264);
  __syncthreads();
  if (w < 3) {
    f32x4 acc = {0.f, 0.f, 0.f, 0.f};
    #pragma unroll
    for (int ks = 0; ks < 8; ++ks) {
      int go = ((ks * 4 + kb) ^ (r0 & 7)) * 8;
      short8 a = *reinterpret_cast<const short8*>(&lA[(w * 16 + r0) * 256 + go]);
      short8 bf = *reinterpret_cast<const short8*>(&qwf[(ks * 64 + lane) * 8]);
      acc = __builtin_amdgcn_mfma_f32_16x16x32_bf16(a, bf, acc, 0, 0, 0);
    }
    if (r0 < 8) {
      float bias = sqb[r0];
      #pragma unroll
      for (int reg = 0; reg < 4; ++reg) {
        int row = w * 16 + kb * 4 + reg;  // D row = (lane>>4)*4+reg (m89-verified)
        if (row < 44) {
          int fo2loc = (row >= 22) ? 1 : 0;
          int j2 = row - fo2loc * 22;
          int fo2 = fp * 2 + fo2loc;
          int lf = (fo2 & 3) * 11264 + j2 * 512 + r0 * 64;
          int t = lf / 1408;
          int s = (lf % 1408) >> 6;
          int h = fo2 >> 2;
          qsum[(((size_t)b * 8 + h) * 32 + t) * 22 + s] = acc[reg] + bias;
        }
      }
    }
  }
}

// ---------------- ksum2: MFMA channel-sums for k ----------------
__global__ __launch_bounds__(512, 2) void ksum2_kernel(const float* __restrict__ k,
                                                       const ushort* __restrict__ kwf,
                                                       const float* __restrict__ skb,
                                                       float* __restrict__ ksumraw) {
  int blk = blockIdx.x;  // b*8 + fp
  int fp = blk & 7, b = blk >> 3;
  __shared__ ushort lA[48 * 256];
  int tid = threadIdx.x, lane = tid & 63, w = tid >> 6;
  int r0 = lane & 15, kb = lane >> 4;
  STAGE44(k + (size_t)blk * 11264);
  __syncthreads();
  if (w < 3) {
    f32x4 acc = {0.f, 0.f, 0.f, 0.f};
    #pragma unroll
    for (int ks = 0; ks < 8; ++ks) {
      int go = ((ks * 4 + kb) ^ (r0 & 7)) * 8;
      short8 a = *reinterpret_cast<const short8*>(&lA[(w * 16 + r0) * 256 + go]);
      short8 bf = *reinterpret_cast<const short8*>(&kwf[(ks * 64 + lane) * 8]);
      acc = __builtin_amdgcn_mfma_f32_16x16x32_bf16(a, bf, acc, 0, 0, 0);
    }
    if (r0 < 8) {
      float bias = skb[r0];
      #pragma unroll
      for (int reg = 0; reg < 4; ++reg) {
        int row = w * 16 + kb * 4 + reg;
        if (row < 44) {
          int f2loc = (row >= 22) ? 1 : 0;
          int j2 = row - f2loc * 22;
          int f2 = fp * 2 + f2loc;
          int lf = (f2 & 1) * 11264 + j2 * 512 + r0 * 64;
          int floc = lf / 1408;
          int jj = (lf % 1408) >> 6;
          int h = f2 >> 1;
          ksumraw[(((size_t)b * 8 + h) * 16 + floc) * 22 + jj] = acc[reg] + bias;
        }
      }
    }
  }
}

// ---------------- ksum_s = conv_s over ksumraw ----------------
__global__ void convk_kernel(const float* __restrict__ ksumraw, const float* __restrict__ csw,
                             const float* __restrict__ csb, float* __restrict__ ksum_s) {
  size_t idx = (size_t)blockIdx.x * 256 + threadIdx.x;
  if (idx >= (size_t)256 * 8 * 32 * 22) return;
  int j = (int)(idx % 22);
  size_t r = idx / 22;
  int o = (int)(r % 32);
  size_t bh = r / 32;
  float acc = 32.0f * csb[o];
  #pragma unroll
  for (int f = 0; f < 16; ++f) acc += csw[o * 16 + f] * ksumraw[(bh * 16 + f) * 22 + j];
  ksum_s[idx] = acc;
}

// ---------------- vproj4: MFMA + 4-phase dump/gather (no atomics) ----------------
__global__ __launch_bounds__(512, 2) void vproj4_kernel(const float* __restrict__ v,
                                                        const ushort* __restrict__ wvtf,
                                                        const float* __restrict__ Wv_b,
                                                        float* __restrict__ vs_inner,
                                                        float* __restrict__ vtsum) {
  int bh = blockIdx.x;  // 0..2047
  __shared__ float sbuf[6656];  // 26.6KB: lA (24.6KB) then dump (512*13 floats)
  ushort* lA = reinterpret_cast<ushort*>(sbuf);
  float* dump = sbuf;
  int tid = threadIdx.x, lane = tid & 63, w = tid >> 6;
  int r0 = lane & 15, kb = lane >> 4;

  STAGE44(v + (size_t)bh * 11264);
  __syncthreads();

  int nt0 = w * 4;
  f32x4 acc[3][4];
  #pragma unroll
  for (int m = 0; m < 3; ++m)
    #pragma unroll
    for (int n = 0; n < 4; ++n) acc[m][n] = (f32x4){0.f, 0.f, 0.f, 0.f};

  #pragma unroll
  for (int ks = 0; ks < 8; ++ks) {
    int go = ((ks * 4 + kb) ^ (r0 & 7)) * 8;
    short8 a0 = *reinterpret_cast<const short8*>(&lA[(r0) * 256 + go]);
    short8 a1 = *reinterpret_cast<const short8*>(&lA[(16 + r0) * 256 + go]);
    short8 a2 = *reinterpret_cast<const short8*>(&lA[(32 + r0) * 256 + go]);
    #pragma unroll
    for (int n = 0; n < 4; ++n) {
      short8 bf = *reinterpret_cast<const short8*>(
          wvtf + ((size_t)((nt0 + n) * 8 + ks) * 64 + lane) * 8);
      acc[0][n] = __builtin_amdgcn_mfma_f32_16x16x32_bf16(bf, a0, acc[0][n], 0, 0, 0);
      acc[1][n] = __builtin_amdgcn_mfma_f32_16x16x32_bf16(bf, a1, acc[1][n], 0, 0, 0);
      acc[2][n] = __builtin_amdgcn_mfma_f32_16x16x32_bf16(bf, a2, acc[2][n], 0, 0, 0);
    }
  }
  __syncthreads();  // lA reads done; sbuf becomes dump

  #pragma unroll
  for (int n = 0; n < 4; ++n) {
    float4 bq = *reinterpret_cast<const float4*>(Wv_b + w * 64 + n * 16 + kb * 4);
    int dbase = tid * 13;
    #pragma unroll
    for (int m = 0; m < 3; ++m) {
      dump[dbase + m * 4 + 0] = acc[m][n][0] + bq.x;
      dump[dbase + m * 4 + 1] = acc[m][n][1] + bq.y;
      dump[dbase + m * 4 + 2] = acc[m][n][2] + bq.z;
      dump[dbase + m * 4 + 3] = acc[m][n][3] + bq.w;
    }
    __syncthreads();
    if (n < 2) {
      // vs outputs for this n: 256 (f 0..15, kb2 0..3, reg 0..3), d = n*16+kb2*4+reg
      if (tid < 256) {
        int f = tid >> 4, rest = tid & 15;
        int kb2 = rest >> 2, reg = rest & 3;
        float s = 0.f;
        #pragma unroll
        for (int u = 0; u < 22; ++u) {
          int fj = f * 22 + u;
          int f2 = (fj >= 176) ? 1 : 0;
          int rem = fj - f2 * 176;
          int j = rem >> 3, ww = rem & 7;
          int vrow = f2 * 22 + j;
          int m = vrow >> 4, rr = vrow & 15;
          s += dump[(ww * 64 + kb2 * 16 + rr) * 13 + m * 4 + reg];
        }
        vs_inner[(size_t)bh * 512 + f * 32 + n * 16 + kb2 * 4 + reg] = s;
      }
    } else {
      // vt outputs for this n: 352 (jj 0..21, kb2, reg), g = (n-2)*16+kb2*4+reg
      if (tid < 352) {
        int jj = tid >> 4, rest = tid & 15;
        int kb2 = rest >> 2, reg = rest & 3;
        float s = 0.f;
        #pragma unroll
        for (int f = 0; f < 16; ++f) {
          int fj = f * 22 + jj;
          int f2 = (fj >= 176) ? 1 : 0;
          int rem = fj - f2 * 176;
          int j = rem >> 3, ww = rem & 7;
          int vrow = f2 * 22 + j;
          int m = vrow >> 4, rr = vrow & 15;
          s += dump[(ww * 64 + kb2 * 16 + rr) * 13 + m * 4 + reg];
        }
        vtsum[(size_t)bh * 704 + jj * 32 + (n - 2) * 16 + kb2 * 4 + reg] = s;
      }
    }
    __syncthreads();
  }
}

// ---------------- vssum = conv_s over vs_inner ----------------
__global__ void convv_kernel(const float* __restrict__ vs_inner, const float* __restrict__ csw,
                             const float* __restrict__ csb, float* __restrict__ vssum) {
  size_t idx = (size_t)blockIdx.x * 256 + threadIdx.x;
  if (idx >= (size_t)256 * 8 * 32 * 32) return;
  int d = (int)(idx & 31);
  size_t r = idx >> 5;
  int t = (int)(r & 31);
  size_t bh = r >> 5;
  float acc = 22.0f * csb[t];
  #pragma unroll
  for (int f = 0; f < 16; ++f) acc += csw[t * 16 + f] * vs_inner[(bh * 16 + f) * 32 + d];
  vssum[idx] = acc;
}

// ---------------- final: diag softmax + assemble output (float4) ----------------
__global__ __launch_bounds__(256) void final_kernel(const float* __restrict__ qsum,
                                                    const float* __restrict__ ksum_s,
                                                    const float* __restrict__ vssum,
                                                    const float* __restrict__ vtsum,
                                                    const int* __restrict__ mask_s,
                                                    float* __restrict__ out) {
  int blk = blockIdx.x;  // b*32 + t
  int t = blk & 31;
  int b = blk >> 5;
  __shared__ float ql[8][22], kl[8][22], vsl[8][32], dg[8][22];
  __shared__ float vtl[8][704];
  __shared__ int msk[484];
  int tid = threadIdx.x;
  size_t bbase = (size_t)b * 8;
  if (tid < 176) {
    int h = tid / 22, s = tid % 22;
    ql[h][s] = qsum[((bbase + h) * 32 + t) * 22 + s];
    kl[h][s] = ksum_s[((bbase + h) * 32 + t) * 22 + s];
  }
  {
    int h = tid >> 5, d = tid & 31;
    vsl[h][d] = vssum[((bbase + h) * 32 + t) * 32 + d];
  }
  {
    float* vtlf = &vtl[0][0];
    const float4* vt4 = reinterpret_cast<const float4*>(vtsum + bbase * 704);
    for (int i4 = tid; i4 < 1408; i4 += 256)
      *reinterpret_cast<float4*>(vtlf + i4 * 4) = vt4[i4];
  }
  for (int idx = tid; idx < 484; idx += 256) msk[idx] = mask_s[idx];
  __syncthreads();
  if (tid < 176) {
    int h = tid / 22, s = tid % 22;
    float qv = ql[h][s];
    float mx = -3.0e38f;
    #pragma unroll
    for (int u = 0; u < 22; ++u) {
      float av = msk[s * 22 + u] ? qv * kl[h][u] : NEGV;
      mx = fmaxf(mx, av);
    }
    float den = 0.f;
    #pragma unroll
    for (int u = 0; u < 22; ++u) {
      float av = msk[s * 22 + u] ? qv * kl[h][u] : NEGV;
      den += expf(av - mx);
    }
    float as = msk[s * 22 + s] ? qv * kl[h][s] : NEGV;
    dg[h][s] = expf(as - mx) / den;
  }
  __syncthreads();
  float4* ob4 = reinterpret_cast<float4*>(out + (size_t)blk * 11264);
  #pragma unroll
  for (int it = 0; it < 11; ++it) {
    int i4 = tid + it * 256;        // 0..2815
    int s = i4 >> 7;                // 128 float4 per s-row
    int ch4 = i4 & 127;
    int h = ch4 >> 4;
    int d0 = (ch4 & 15) * 4;
    float4 val;
    if (d0 < 32) {
      float g = dg[h][s];
      const float* vp = &vsl[h][d0];
      val.x = g * vp[0]; val.y = g * vp[1]; val.z = g * vp[2]; val.w = g * vp[3];
    } else {
      const float* tp = &vtl[h][s * 32 + d0 - 32];
      val.x = tp[0]; val.y = tp[1]; val.z = tp[2]; val.w = tp[3];
    }
    ob4[i4] = val;
  }
}

extern "C" void kernel_launch(void* const* d_in, const int* in_sizes, int n_in,
                              void* d_out, int out_size, void* d_ws, size_t ws_size,
                              hipStream_t stream) {
  const float* q = (const float*)d_in[0];
  const float* k = (const float*)d_in[1];
  const float* v = (const float*)d_in[2];
  const int* mask_s = (const int*)d_in[3];
  const float* Wq_b = (const float*)d_in[6];
  const float* Wq_w = (const float*)d_in[5];
  const float* Wk_w = (const float*)d_in[7];
  const float* Wk_b = (const float*)d_in[8];
  const float* Wv_w = (const float*)d_in[9];
  const float* Wv_b = (const float*)d_in[10];
  const float* csw = (const float*)d_in[11];
  const float* csb = (const float*)d_in[12];
  float* out = (float*)d_out;

  float* ws = (float*)d_ws;
  float* sqb = ws;                            // 8
  float* skb = ws + 8;                        // 8 -> 16
  ushort* wvtf = (ushort*)(ws + 16);          // 131072 us = 65536 f -> ends 65552
  ushort* qwf = (ushort*)(ws + 65552);        // 4096 us = 2048 f -> 67600
  ushort* kwf = (ushort*)(ws + 67600);        // 2048 f -> 69648
  float* qsum = ws + 69648;                   // 1441792
  float* ksumraw = qsum + 1441792;            // 720896
  float* ksum_s = ksumraw + 720896;           // 1441792
  float* vs_inner = ksum_s + 1441792;         // 1048576
  float* vtsum = vs_inner + 1048576;          // 1441792
  float* vssum = vtsum + 1441792;             // 2097152

  hipLaunchKernelGGL(prepb_kernel, dim3(1), dim3(64), 0, stream, Wq_b, Wk_b, sqb, skb);
  hipLaunchKernelGGL(qkwf_kernel, dim3(16), dim3(512), 0, stream, Wq_w, Wk_w, qwf, kwf);
  hipLaunchKernelGGL(wvt_kernel, dim3(256), dim3(512), 0, stream, Wv_w, wvtf);
  hipLaunchKernelGGL(qsum2_kernel, dim3(4096), dim3(512), 0, stream, q, qwf, sqb, qsum);
  hipLaunchKernelGGL(ksum2_kernel, dim3(2048), dim3(512), 0, stream, k, kwf, skb, ksumraw);
  hipLaunchKernelGGL(convk_kernel, dim3(5632), dim3(256), 0, stream, ksumraw, csw, csb, ksum_s);
  hipLaunchKernelGGL(vproj4_kernel, dim3(2048), dim3(512), 0, stream,
                     v, wvtf, Wv_b, vs_inner, vtsum);
  hipLaunchKernelGGL(convv_kernel, dim3(8192), dim3(256), 0, stream, vs_inner, csw, csb, vssum);
  hipLaunchKernelGGL(final_kernel, dim3(8192), dim3(256), 0, stream,
                     qsum, ksum_s, vssum, vtsum, mask_s, out);
}

// Round 10
// 259.413 us; speedup vs baseline: 2.0816x; 1.0838x over previous
//
#include <hip/hip_runtime.h>

// B=256, F=16, FO=32, J=22, H=8, IN=256, OUT=512, HID=64, HS=32
// Degenerate-einsum analysis:
//   attn_s = qsum (x) ksum  (outer product of channel sums)
//   x_s    = diag(softmax(attn_s)) * (sum_u v_s')
//   x_t    = sum_f v_t  (softmax sums to 1; q_t/k_t/conv_t/mask_t unused)
// Round 10: R9 structure (3 kernels), fixing the final2 lcw staging bug:
// old predicate (tid>=484 && tid<516) never covered lcw[1][12..15] (tid<512).
// Now tid<32 loads all 32 csw taps, tid 32/33 load the 2 csb biases.

#define NEGV (-1000000000.0f)

typedef __attribute__((ext_vector_type(8))) short short8;
typedef __attribute__((ext_vector_type(4))) float f32x4;

__device__ inline ushort f2bf(float f) {
  union { float f; unsigned u; } a;
  a.f = f;
  unsigned u = a.u;
  return (ushort)((u + 0x7FFFu + ((u >> 16) & 1u)) >> 16);  // RNE
}

// stage 44 rows x 256 f32 -> bf16 into lA with granule swizzle gp = gl ^ (row&7)
#define PUTG(g, pa, pb)                                                        \
  {                                                                            \
    int row_ = (g) >> 5, gl_ = (g) & 31;                                       \
    int gp_ = gl_ ^ (row_ & 7);                                                \
    short8 u_;                                                                 \
    u_[0] = (short)f2bf(pa.x); u_[1] = (short)f2bf(pa.y);                      \
    u_[2] = (short)f2bf(pa.z); u_[3] = (short)f2bf(pa.w);                      \
    u_[4] = (short)f2bf(pb.x); u_[5] = (short)f2bf(pb.y);                      \
    u_[6] = (short)f2bf(pb.z); u_[7] = (short)f2bf(pb.w);                      \
    *reinterpret_cast<short8*>(&lA[row_ * 256 + gp_ * 8]) = u_;                \
  }

#define STAGE44(SRCPTR)                                                        \
  {                                                                            \
    const float* vsrc_ = (SRCPTR);                                             \
    int g0 = tid, g1 = tid + 512, g2 = tid + 1024;                             \
    float4 a0 = *reinterpret_cast<const float4*>(vsrc_ + g0 * 8);              \
    float4 b0 = *reinterpret_cast<const float4*>(vsrc_ + g0 * 8 + 4);          \
    float4 a1 = *reinterpret_cast<const float4*>(vsrc_ + g1 * 8);              \
    float4 b1 = *reinterpret_cast<const float4*>(vsrc_ + g1 * 8 + 4);          \
    float4 a2 = {0, 0, 0, 0}, b2 = {0, 0, 0, 0};                               \
    if (g2 < 1408) {                                                           \
      a2 = *reinterpret_cast<const float4*>(vsrc_ + g2 * 8);                   \
      b2 = *reinterpret_cast<const float4*>(vsrc_ + g2 * 8 + 4);               \
    }                                                                          \
    PUTG(g0, a0, b0);                                                          \
    PUTG(g1, a1, b1);                                                          \
    if (g2 < 1408) PUTG(g2, a2, b2);                                           \
    if (tid < 128) {                                                           \
      int g = 1408 + tid;                                                      \
      int row_ = g >> 5, gp_ = (g & 31) ^ (row_ & 7);                          \
      short8 z = {0, 0, 0, 0, 0, 0, 0, 0};                                     \
      *reinterpret_cast<short8*>(&lA[row_ * 256 + gp_ * 8]) = z;               \
    }                                                                          \
  }

// ---------------- prep_all: wvt (0..255) + qkwf (256..271) + prepb (272) ----
__global__ __launch_bounds__(512) void prep_all_kernel(const float* __restrict__ Wq_w,
                                                       const float* __restrict__ Wq_b,
                                                       const float* __restrict__ Wk_w,
                                                       const float* __restrict__ Wk_b,
                                                       const float* __restrict__ Wv_w,
                                                       ushort* __restrict__ qwf,
                                                       ushort* __restrict__ kwf,
                                                       ushort* __restrict__ wvtf,
                                                       float* __restrict__ sqb,
                                                       float* __restrict__ skb) {
  int bx = blockIdx.x, tid = threadIdx.x;
  if (bx < 256) {
    int idx = bx * 512 + tid;  // 0..131071
    int e = idx & 7;
    int lane = (idx >> 3) & 63;
    int ks = (idx >> 9) & 7;
    int nt = idx >> 12;
    int r0 = lane & 15, kb = lane >> 4;
    int k = ks * 32 + kb * 8 + e;
    int ch = nt * 16 + r0;
    wvtf[idx] = f2bf(Wv_w[k * 512 + ch]);
  } else if (bx < 272) {
    int idx = (bx - 256) * 512 + tid;  // 0..8191
    int which = idx >> 12;
    int r = idx & 4095;
    int e = r & 7;
    int lane = (r >> 3) & 63;
    int ks = r >> 9;
    int m = lane & 15, kb = lane >> 4;
    int k = ks * 32 + kb * 8 + e;
    float s = 0.f;
    if (m < 8) {
      const float* W = which ? Wk_w : Wq_w;
      const float4* p = reinterpret_cast<const float4*>(W + (size_t)k * 512 + m * 64);
      #pragma unroll
      for (int c4 = 0; c4 < 8; ++c4) {
        float4 x = p[c4];
        s += x.x + x.y + x.z + x.w;
      }
    }
    (which ? kwf : qwf)[r] = f2bf(s);
  } else {
    if (tid < 8) {
      float s = 0.f;
      for (int c = 0; c < 32; ++c) s += Wq_b[tid * 64 + c];
      sqb[tid] = s;
    } else if (tid < 16) {
      int mm = tid - 8;
      float s = 0.f;
      for (int c = 0; c < 32; ++c) s += Wk_b[mm * 64 + c];
      skb[mm] = s;
    }
  }
}

// ---------------- fused_mfma: qsum (0..4095) + ksum (4096..6143) + vproj ----
__global__ __launch_bounds__(512, 2) void fused_mfma_kernel(const float* __restrict__ q,
                                                            const float* __restrict__ k,
                                                            const float* __restrict__ v,
                                                            const ushort* __restrict__ qwf,
                                                            const ushort* __restrict__ kwf,
                                                            const ushort* __restrict__ wvtf,
                                                            const float* __restrict__ sqb,
                                                            const float* __restrict__ skb,
                                                            const float* __restrict__ Wv_b,
                                                            float* __restrict__ qsum,
                                                            float* __restrict__ ksumraw,
                                                            float* __restrict__ vs_inner,
                                                            float* __restrict__ vtsum) {
  int bx = blockIdx.x;
  __shared__ float sbuf[6656];  // 26.6KB: lA (24.6KB); vproj reuses as dump
  ushort* lA = reinterpret_cast<ushort*>(sbuf);
  float* dump = sbuf;
  int tid = threadIdx.x, lane = tid & 63, w = tid >> 6;
  int r0 = lane & 15, kb = lane >> 4;

  if (bx < 4096) {
    // ---- qsum branch ----
    int blk = bx;
    int fp = blk & 15, b = blk >> 4;
    STAGE44(q + (size_t)blk * 11264);
    __syncthreads();
    if (w < 3) {
      f32x4 acc = {0.f, 0.f, 0.f, 0.f};
      #pragma unroll
      for (int ks = 0; ks < 8; ++ks) {
        int go = ((ks * 4 + kb) ^ (r0 & 7)) * 8;
        short8 a = *reinterpret_cast<const short8*>(&lA[(w * 16 + r0) * 256 + go]);
        short8 bf = *reinterpret_cast<const short8*>(&qwf[(ks * 64 + lane) * 8]);
        acc = __builtin_amdgcn_mfma_f32_16x16x32_bf16(a, bf, acc, 0, 0, 0);
      }
      if (r0 < 8) {
        float bias = sqb[r0];
        #pragma unroll
        for (int reg = 0; reg < 4; ++reg) {
          int row = w * 16 + kb * 4 + reg;  // D row = (lane>>4)*4+reg (m89-verified)
          if (row < 44) {
            int fo2loc = (row >= 22) ? 1 : 0;
            int j2 = row - fo2loc * 22;
            int fo2 = fp * 2 + fo2loc;
            int lf = (fo2 & 3) * 11264 + j2 * 512 + r0 * 64;
            int t = lf / 1408;
            int s = (lf % 1408) >> 6;
            int h = fo2 >> 2;
            qsum[(((size_t)b * 8 + h) * 32 + t) * 22 + s] = acc[reg] + bias;
          }
        }
      }
    }
  } else if (bx < 6144) {
    // ---- ksum branch ----
    int blk = bx - 4096;
    int fp = blk & 7, b = blk >> 3;
    STAGE44(k + (size_t)blk * 11264);
    __syncthreads();
    if (w < 3) {
      f32x4 acc = {0.f, 0.f, 0.f, 0.f};
      #pragma unroll
      for (int ks = 0; ks < 8; ++ks) {
        int go = ((ks * 4 + kb) ^ (r0 & 7)) * 8;
        short8 a = *reinterpret_cast<const short8*>(&lA[(w * 16 + r0) * 256 + go]);
        short8 bf = *reinterpret_cast<const short8*>(&kwf[(ks * 64 + lane) * 8]);
        acc = __builtin_amdgcn_mfma_f32_16x16x32_bf16(a, bf, acc, 0, 0, 0);
      }
      if (r0 < 8) {
        float bias = skb[r0];
        #pragma unroll
        for (int reg = 0; reg < 4; ++reg) {
          int row = w * 16 + kb * 4 + reg;
          if (row < 44) {
            int f2loc = (row >= 22) ? 1 : 0;
            int j2 = row - f2loc * 22;
            int f2 = fp * 2 + f2loc;
            int lf = (f2 & 1) * 11264 + j2 * 512 + r0 * 64;
            int floc = lf / 1408;
            int jj = (lf % 1408) >> 6;
            int h = f2 >> 1;
            ksumraw[(((size_t)b * 8 + h) * 16 + floc) * 22 + jj] = acc[reg] + bias;
          }
        }
      }
    }
  } else {
    // ---- vproj branch (dump/gather, no atomics) ----
    int bh = bx - 6144;
    STAGE44(v + (size_t)bh * 11264);
    __syncthreads();

    int nt0 = w * 4;
    f32x4 acc[3][4];
    #pragma unroll
    for (int m = 0; m < 3; ++m)
      #pragma unroll
      for (int n = 0; n < 4; ++n) acc[m][n] = (f32x4){0.f, 0.f, 0.f, 0.f};

    #pragma unroll
    for (int ks = 0; ks < 8; ++ks) {
      int go = ((ks * 4 + kb) ^ (r0 & 7)) * 8;
      short8 a0 = *reinterpret_cast<const short8*>(&lA[(r0) * 256 + go]);
      short8 a1 = *reinterpret_cast<const short8*>(&lA[(16 + r0) * 256 + go]);
      short8 a2 = *reinterpret_cast<const short8*>(&lA[(32 + r0) * 256 + go]);
      #pragma unroll
      for (int n = 0; n < 4; ++n) {
        short8 bf = *reinterpret_cast<const short8*>(
            wvtf + ((size_t)((nt0 + n) * 8 + ks) * 64 + lane) * 8);
        acc[0][n] = __builtin_amdgcn_mfma_f32_16x16x32_bf16(bf, a0, acc[0][n], 0, 0, 0);
        acc[1][n] = __builtin_amdgcn_mfma_f32_16x16x32_bf16(bf, a1, acc[1][n], 0, 0, 0);
        acc[2][n] = __builtin_amdgcn_mfma_f32_16x16x32_bf16(bf, a2, acc[2][n], 0, 0, 0);
      }
    }
    __syncthreads();  // lA reads done; sbuf becomes dump

    #pragma unroll
    for (int n = 0; n < 4; ++n) {
      float4 bq = *reinterpret_cast<const float4*>(Wv_b + w * 64 + n * 16 + kb * 4);
      int dbase = tid * 13;
      #pragma unroll
      for (int m = 0; m < 3; ++m) {
        dump[dbase + m * 4 + 0] = acc[m][n][0] + bq.x;
        dump[dbase + m * 4 + 1] = acc[m][n][1] + bq.y;
        dump[dbase + m * 4 + 2] = acc[m][n][2] + bq.z;
        dump[dbase + m * 4 + 3] = acc[m][n][3] + bq.w;
      }
      __syncthreads();
      if (n < 2) {
        if (tid < 256) {
          int f = tid >> 4, rest = tid & 15;
          int kb2 = rest >> 2, reg = rest & 3;
          float s = 0.f;
          #pragma unroll
          for (int u = 0; u < 22; ++u) {
            int fj = f * 22 + u;
            int f2 = (fj >= 176) ? 1 : 0;
            int rem = fj - f2 * 176;
            int j = rem >> 3, ww = rem & 7;
            int vrow = f2 * 22 + j;
            int m = vrow >> 4, rr = vrow & 15;
            s += dump[(ww * 64 + kb2 * 16 + rr) * 13 + m * 4 + reg];
          }
          vs_inner[(size_t)bh * 512 + f * 32 + n * 16 + kb2 * 4 + reg] = s;
        }
      } else {
        if (tid < 352) {
          int jj = tid >> 4, rest = tid & 15;
          int kb2 = rest >> 2, reg = rest & 3;
          float s = 0.f;
          #pragma unroll
          for (int f = 0; f < 16; ++f) {
            int fj = f * 22 + jj;
            int f2 = (fj >= 176) ? 1 : 0;
            int rem = fj - f2 * 176;
            int j = rem >> 3, ww = rem & 7;
            int vrow = f2 * 22 + j;
            int m = vrow >> 4, rr = vrow & 15;
            s += dump[(ww * 64 + kb2 * 16 + rr) * 13 + m * 4 + reg];
          }
          vtsum[(size_t)bh * 704 + jj * 32 + (n - 2) * 16 + kb2 * 4 + reg] = s;
        }
      }
      __syncthreads();
    }
  }
}

// ---------------- final2: conv_s (k & v) + diag softmax + output, 2 t/block --
__global__ __launch_bounds__(512, 2) void final2_kernel(const float* __restrict__ qsum,
                                                        const float* __restrict__ ksumraw,
                                                        const float* __restrict__ vs_inner,
                                                        const float* __restrict__ vtsum,
                                                        const int* __restrict__ mask_s,
                                                        const float* __restrict__ csw,
                                                        const float* __restrict__ csb,
                                                        float* __restrict__ out) {
  int blk = blockIdx.x;  // b*16 + tp
  int tp = blk & 15, b = blk >> 4;
  int t0 = tp * 2;
  __shared__ float vtl[8][704];      // 5632
  __shared__ float vsi[8][16][32];   // 4096
  __shared__ float kraw[8][16][22];  // 2816
  __shared__ float ql2[2][8][22];
  __shared__ float klrow[2][8][22];
  __shared__ float vss[2][8][32];
  __shared__ float dg2[2][8][22];
  __shared__ float lcw[2][18];
  __shared__ int msk[484];
  int tid = threadIdx.x;
  size_t bb = (size_t)b;

  {
    const float4* p = reinterpret_cast<const float4*>(vtsum + bb * 5632);
    float4* dst = reinterpret_cast<float4*>(&vtl[0][0]);
    for (int i = tid; i < 1408; i += 512) dst[i] = p[i];
  }
  {
    const float4* p = reinterpret_cast<const float4*>(vs_inner + bb * 4096);
    float4* dst = reinterpret_cast<float4*>(&vsi[0][0][0]);
    for (int i = tid; i < 1024; i += 512) dst[i] = p[i];
  }
  {
    const float4* p = reinterpret_cast<const float4*>(ksumraw + bb * 2816);
    float4* dst = reinterpret_cast<float4*>(&kraw[0][0][0]);
    for (int i = tid; i < 704; i += 512) dst[i] = p[i];
  }
  if (tid < 352) {
    int tt = tid / 176, r = tid % 176;
    int h = r / 22, s = r % 22;
    ql2[tt][h][s] = qsum[((bb * 8 + h) * 32 + t0 + tt) * 22 + s];
  }
  if (tid < 484) msk[tid] = mask_s[tid];
  // FIX (R9 bug): full coverage of lcw[2][16] + biases; old predicate
  // (tid>=484 && tid<516) never executed for x>27 since tid<512.
  if (tid < 32) {
    int tt = tid >> 4, f = tid & 15;
    lcw[tt][f] = csw[(t0 + tt) * 16 + f];
  }
  if (tid >= 32 && tid < 34) lcw[tid - 32][16] = csb[t0 + (tid - 32)];
  __syncthreads();

  // conv_s on ksumraw row t, and on vs_inner row t
  if (tid < 352) {
    int tt = tid / 176, r = tid % 176;
    int h = r / 22, j = r % 22;
    float a = 32.0f * lcw[tt][16];
    #pragma unroll
    for (int f = 0; f < 16; ++f) a += lcw[tt][f] * kraw[h][f][j];
    klrow[tt][h][j] = a;
  }
  {
    int tt = tid >> 8, r = tid & 255;
    int h = r >> 5, d = r & 31;
    float a = 22.0f * lcw[tt][16];
    #pragma unroll
    for (int f = 0; f < 16; ++f) a += lcw[tt][f] * vsi[h][f][d];
    vss[tt][h][d] = a;
  }
  __syncthreads();

  if (tid < 352) {
    int tt = tid / 176, r = tid % 176;
    int h = r / 22, s = r % 22;
    float qv = ql2[tt][h][s];
    float mx = -3.0e38f;
    #pragma unroll
    for (int u = 0; u < 22; ++u) {
      float av = msk[s * 22 + u] ? qv * klrow[tt][h][u] : NEGV;
      mx = fmaxf(mx, av);
    }
    float den = 0.f;
    #pragma unroll
    for (int u = 0; u < 22; ++u) {
      float av = msk[s * 22 + u] ? qv * klrow[tt][h][u] : NEGV;
      den += expf(av - mx);
    }
    float as = msk[s * 22 + s] ? qv * klrow[tt][h][s] : NEGV;
    dg2[tt][h][s] = expf(as - mx) / den;
  }
  __syncthreads();

  #pragma unroll
  for (int tt = 0; tt < 2; ++tt) {
    float4* ob4 = reinterpret_cast<float4*>(out + (size_t)(b * 32 + t0 + tt) * 11264);
    #pragma unroll
    for (int it = 0; it < 6; ++it) {
      int i4 = tid + it * 512;  // 0..2815
      if (i4 < 2816) {
        int s = i4 >> 7;
        int ch4 = i4 & 127;
        int h = ch4 >> 4;
        int d0 = (ch4 & 15) * 4;
        float4 val;
        if (d0 < 32) {
          float g = dg2[tt][h][s];
          const float* vp = &vss[tt][h][d0];
          val.x = g * vp[0]; val.y = g * vp[1]; val.z = g * vp[2]; val.w = g * vp[3];
        } else {
          const float* tpn = &vtl[h][s * 32 + d0 - 32];
          val.x = tpn[0]; val.y = tpn[1]; val.z = tpn[2]; val.w = tpn[3];
        }
        ob4[i4] = val;
      }
    }
  }
}

extern "C" void kernel_launch(void* const* d_in, const int* in_sizes, int n_in,
                              void* d_out, int out_size, void* d_ws, size_t ws_size,
                              hipStream_t stream) {
  const float* q = (const float*)d_in[0];
  const float* k = (const float*)d_in[1];
  const float* v = (const float*)d_in[2];
  const int* mask_s = (const int*)d_in[3];
  const float* Wq_w = (const float*)d_in[5];
  const float* Wq_b = (const float*)d_in[6];
  const float* Wk_w = (const float*)d_in[7];
  const float* Wk_b = (const float*)d_in[8];
  const float* Wv_w = (const float*)d_in[9];
  const float* Wv_b = (const float*)d_in[10];
  const float* csw = (const float*)d_in[11];
  const float* csb = (const float*)d_in[12];
  float* out = (float*)d_out;

  float* ws = (float*)d_ws;
  float* sqb = ws;                            // 8
  float* skb = ws + 8;                        // 8 -> 16
  ushort* wvtf = (ushort*)(ws + 16);          // 131072 us -> ends f-idx 65552
  ushort* qwf = (ushort*)(ws + 65552);        // 4096 us -> 67600
  ushort* kwf = (ushort*)(ws + 67600);        // 4096 us -> 69648
  float* qsum = ws + 69648;                   // 1441792
  float* ksumraw = qsum + 1441792;            // 720896
  float* vs_inner = ksumraw + 720896;         // 1048576
  float* vtsum = vs_inner + 1048576;          // 1441792

  hipLaunchKernelGGL(prep_all_kernel, dim3(273), dim3(512), 0, stream,
                     Wq_w, Wq_b, Wk_w, Wk_b, Wv_w, qwf, kwf, wvtf, sqb, skb);
  hipLaunchKernelGGL(fused_mfma_kernel, dim3(8192), dim3(512), 0, stream,
                     q, k, v, qwf, kwf, wvtf, sqb, skb, Wv_b,
                     qsum, ksumraw, vs_inner, vtsum);
  hipLaunchKernelGGL(final2_kernel, dim3(4096), dim3(512), 0, stream,
                     qsum, ksumraw, vs_inner, vtsum, mask_s, csw, csb, out);
}